// Round 6
// baseline (264.472 us; speedup 1.0000x reference)
//
#include <hip/hip_runtime.h>
#include <hip/hip_bf16.h>

typedef __attribute__((ext_vector_type(8))) short short8;
typedef __attribute__((ext_vector_type(4))) short s16x4;
typedef __attribute__((ext_vector_type(4))) float f32x4;
typedef __attribute__((ext_vector_type(4))) _Float16 h4;

typedef const __attribute__((address_space(1))) unsigned* gp1;
typedef __attribute__((address_space(3))) unsigned* lp3;

__device__ inline short f2bf(float f) {
    union { float f; unsigned u; } v; v.f = f;
    unsigned r = v.u + 0x7fffu + ((v.u >> 16) & 1u);
    return (short)(r >> 16);
}

// ---------------------------------------------------------------------------
// P0: fp32 -> bf16 flat convert (x)
// ---------------------------------------------------------------------------
__global__ __launch_bounds__(256) void cvt_bf16(
    const float* __restrict__ src, short* __restrict__ dst, int n4)
{
    int i = blockIdx.x * 256 + threadIdx.x;
    if (i < n4) {
        float4 v = ((const float4*)src)[i];
        s16x4 o = { f2bf(v.x), f2bf(v.y), f2bf(v.z), f2bf(v.w) };
        ((s16x4*)dst)[i] = o;
    }
}

// ---------------------------------------------------------------------------
// P0b: spd fp32 -> fp16 (halves spd bytes for attn; values ~N(0,1), fp16 safe)
// ---------------------------------------------------------------------------
__global__ __launch_bounds__(256) void cvt_spd(
    const float* __restrict__ src, _Float16* __restrict__ dst, int n4)
{
    int i = blockIdx.x * 256 + threadIdx.x;
    if (i < n4) {
        float4 v = ((const float4*)src)[i];
        h4 o = { (_Float16)v.x, (_Float16)v.y, (_Float16)v.z, (_Float16)v.w };
        ((h4*)dst)[i] = o;
    }
}

// ---------------------------------------------------------------------------
// P1: W[K][N] fp32 -> W^T[N][K] bf16 (64x64 LDS tile transpose)
// ---------------------------------------------------------------------------
__global__ __launch_bounds__(256) void tr_w(
    const float* __restrict__ src, short* __restrict__ dst, int K, int N)
{
    __shared__ float t[64][65];
    const int k0 = blockIdx.x * 64, n0 = blockIdx.y * 64;
    const int r = threadIdx.x >> 4, c4 = (threadIdx.x & 15) * 4;
#pragma unroll
    for (int j = 0; j < 4; j++) {
        float4 v = *(const float4*)(src + (size_t)(k0 + r + 16 * j) * N + n0 + c4);
        t[r + 16 * j][c4 + 0] = v.x; t[r + 16 * j][c4 + 1] = v.y;
        t[r + 16 * j][c4 + 2] = v.z; t[r + 16 * j][c4 + 3] = v.w;
    }
    __syncthreads();
#pragma unroll
    for (int j = 0; j < 4; j++) {
        const int n = r + 16 * j;
        s16x4 o = { f2bf(t[c4 + 0][n]), f2bf(t[c4 + 1][n]),
                    f2bf(t[c4 + 2][n]), f2bf(t[c4 + 3][n]) };
        *(s16x4*)(dst + (size_t)(n0 + n) * K + k0 + c4) = o;
    }
}

// ---------------------------------------------------------------------------
// P2: v[bh][n][64] bf16 -> vt[bh][d][n] bf16 (64x64 tile transpose).
//     Replaces qkv_gemm's 2B-scattered vt stores (stride-2KB scalar writes).
// ---------------------------------------------------------------------------
__global__ __launch_bounds__(256) void tr_v(
    const short* __restrict__ src, short* __restrict__ dst)
{
    __shared__ short t[64][72];
    const int bh = blockIdx.y, n0 = blockIdx.x * 64;
    const int r = threadIdx.x >> 3;          // 0..31
    const int c8 = (threadIdx.x & 7) * 8;    // 0..56
    const short* s = src + ((size_t)bh * 1024 + n0) * 64;
#pragma unroll
    for (int j = 0; j < 2; j++) {
        short8 v = *(const short8*)(s + (size_t)(r + 32 * j) * 64 + c8);
        *(short8*)&t[r + 32 * j][c8] = v;
    }
    __syncthreads();
    short* dptr = dst + (size_t)bh * 65536;
#pragma unroll
    for (int j = 0; j < 2; j++) {
        const int d = r + 32 * j;
        s16x4 lo = { t[c8 + 0][d], t[c8 + 1][d], t[c8 + 2][d], t[c8 + 3][d] };
        s16x4 hi = { t[c8 + 4][d], t[c8 + 5][d], t[c8 + 6][d], t[c8 + 7][d] };
        *(s16x4*)(dptr + (size_t)d * 1024 + n0 + c8)     = lo;
        *(s16x4*)(dptr + (size_t)d * 1024 + n0 + c8 + 4) = hi;
    }
}

// ---------------------------------------------------------------------------
// K1: qkv = xb @ WqT^T  (M=8192, K=512, N=1536), m97-style 128x128 tile.
//     v-section now writes COALESCED [bh][n][d] (same as k); tr_v transposes.
// ---------------------------------------------------------------------------
__global__ __launch_bounds__(256) void qkv_gemm(
    const short* __restrict__ A, const short* __restrict__ BT,
    short* __restrict__ q, short* __restrict__ k, short* __restrict__ vw)
{
    __shared__ short sA[128][32];   // NO padding: global_load_lds needs dense
    __shared__ short sB[128][32];

    const int tid  = threadIdx.x;
    const int wv   = tid >> 6, lane = tid & 63;
    const int quad = lane >> 4, l16 = lane & 15;
    const int wr = wv >> 1, wc = wv & 1;
    const int m0 = blockIdx.x * 128, n0 = blockIdx.y * 128;

    f32x4 acc[4][4];
#pragma unroll
    for (int i = 0; i < 4; i++)
#pragma unroll
        for (int j = 0; j < 4; j++) acc[i][j] = (f32x4){0.f, 0.f, 0.f, 0.f};

    const short* a_src = A  + (size_t)(m0 + wv * 32 + (lane >> 2)) * 512 + (lane & 3) * 8;
    const short* b_src = BT + (size_t)(n0 + wv * 32 + (lane >> 2)) * 512 + (lane & 3) * 8;
    char* a_dst = (char*)sA + wv * 2048;
    char* b_dst = (char*)sB + wv * 2048;

    for (int ks = 0; ks < 16; ks++) {
        __syncthreads();
        const short* ap = a_src + ks * 32;
        const short* bp = b_src + ks * 32;
        __builtin_amdgcn_global_load_lds((gp1)(ap),            (lp3)(a_dst),        16, 0, 0);
        __builtin_amdgcn_global_load_lds((gp1)(ap + 16 * 512), (lp3)(a_dst + 1024), 16, 0, 0);
        __builtin_amdgcn_global_load_lds((gp1)(bp),            (lp3)(b_dst),        16, 0, 0);
        __builtin_amdgcn_global_load_lds((gp1)(bp + 16 * 512), (lp3)(b_dst + 1024), 16, 0, 0);
        __syncthreads();

        short8 af[4], bf[4];
#pragma unroll
        for (int f = 0; f < 4; f++) {
            af[f] = *(const short8*)&sA[wr * 64 + f * 16 + l16][quad * 8];
            bf[f] = *(const short8*)&sB[wc * 64 + f * 16 + l16][quad * 8];
        }
#pragma unroll
        for (int fm = 0; fm < 4; fm++)
#pragma unroll
            for (int fn = 0; fn < 4; fn++)
                acc[fm][fn] = __builtin_amdgcn_mfma_f32_16x16x32_bf16(
                    af[fm], bf[fn], acc[fm][fn], 0, 0, 0);
    }

    const int sec = n0 >> 9;   // 0=q 1=k 2=v
#pragma unroll
    for (int fn = 0; fn < 4; fn++) {
        const int gc = n0 + wc * 64 + fn * 16 + l16;
        const int cc = gc & 511;
        const int h = cc >> 6, d = cc & 63;
#pragma unroll
        for (int fm = 0; fm < 4; fm++)
#pragma unroll
            for (int i = 0; i < 4; i++) {
                const int gm = m0 + wr * 64 + fm * 16 + quad * 4 + i;
                const int b = gm >> 10, n = gm & 1023;
                const int bh = b * 8 + h;
                if (sec == 0)      q[((size_t)(bh * 1024 + n)) * 64 + d]  = f2bf(acc[fm][fn][i] * 0.125f);
                else if (sec == 1) k[((size_t)(bh * 1024 + n)) * 64 + d]  = f2bf(acc[fm][fn][i]);
                else               vw[((size_t)(bh * 1024 + n)) * 64 + d] = f2bf(acc[fm][fn][i]);
            }
    }
}

// ---------------------------------------------------------------------------
// K2: attention (R5 structure + R6: fp16 spd, sweep1 K double-buffer with a
//     single barrier per chunk and 2-register-set prefetch).
//   Block = (bh, 64 q-rows), 4 waves x 16 q-rows; K/V staged to LDS in 64-key
//   chunks shared by all waves. Sweep1 = row norms; sweep2 = bias + online
//   softmax (+cross-domain fo shuffle fix from R5) + PV.
//   LDS: sK dbuf 18.4K + sV 9.2K + sP 9.2K + sred = 37.1 KB -> 4 blocks/CU.
//   Tripwire: WRITE_SIZE must stay ~8.2 MB (no spill).
// ---------------------------------------------------------------------------
__global__ __launch_bounds__(256, 4) void attn_k(
    const short* __restrict__ q, const short* __restrict__ kk,
    const short* __restrict__ vt, const _Float16* __restrict__ spdh,
    const float* __restrict__ hm, short* __restrict__ o)
{
    __shared__ short sK[2][64][72];
    __shared__ short sV[64][72];
    __shared__ short sP[4][16][72];
    __shared__ float sred[4][16];

    const int tid  = threadIdx.x;
    const int wv   = tid >> 6, lane = tid & 63;
    const int quad = lane >> 4, l16 = lane & 15;
    const int qt = blockIdx.x, bh = blockIdx.y;
    const int b = bh >> 3, h = bh & 7;
    const int q0 = qt * 64;

    // Q as B-operand: lane l16 = q-col, quad*8 = d
    const short* qb = q + ((size_t)bh * 1024 + q0 + wv * 16 + l16) * 64;
    short8 aq0 = *(const short8*)(qb + quad * 8);
    short8 aq1 = *(const short8*)(qb + 32 + quad * 8);

    // staging map: thread -> row sr (and sr+32), 16B col chunk sc
    const int sr = tid & 31, sc = (tid >> 5) * 8;
    const short* ksrc = kk + (size_t)bh * 65536 + (size_t)sr * 64 + sc;    // keys as rows
    const short* vsrc = vt + (size_t)bh * 65536 + (size_t)sr * 1024 + sc;  // d as rows
    const _Float16* sph = spdh + ((size_t)b * 1024 + q0 + wv * 16 + l16) * 1024 + quad * 4;

    // ================= sweep 1: row norms (dbuf K, ONE barrier/chunk) ======
    float dn = 0.f, pn = 0.f;
    short8 ka0 = *(const short8*)(ksrc);
    short8 ka1 = *(const short8*)(ksrc + 2048);
    short8 kb0 = *(const short8*)(ksrc + 4096);
    short8 kb1 = *(const short8*)(ksrc + 4096 + 2048);
    h4 sv0 = *(const h4*)(sph +  0);
    h4 sv1 = *(const h4*)(sph + 16);
    h4 sv2 = *(const h4*)(sph + 32);
    h4 sv3 = *(const h4*)(sph + 48);
    *(short8*)&sK[0][sr][sc]      = ka0;
    *(short8*)&sK[0][sr + 32][sc] = ka1;
    __syncthreads();

    for (int c = 0; c < 16; ++c) {
        const int cur = c & 1;
        // stage chunk c+1 into the other buffer (regs loaded >=1 chunk ago).
        // safe: buffer cur^1 was last read in chunk c-1; barrier at end of c-1.
        if (c < 15) {
            if (c & 1) { *(short8*)&sK[cur ^ 1][sr][sc] = ka0; *(short8*)&sK[cur ^ 1][sr + 32][sc] = ka1; }
            else       { *(short8*)&sK[cur ^ 1][sr][sc] = kb0; *(short8*)&sK[cur ^ 1][sr + 32][sc] = kb1; }
        }
        // refill the just-freed register set with chunk c+2
        if (c < 14) {
            if (c & 1) { kb0 = *(const short8*)(ksrc + (c + 2) * 4096);
                         kb1 = *(const short8*)(ksrc + (c + 2) * 4096 + 2048); }
            else       { ka0 = *(const short8*)(ksrc + (c + 2) * 4096);
                         ka1 = *(const short8*)(ksrc + (c + 2) * 4096 + 2048); }
        }
        h4 svc[4] = { sv0, sv1, sv2, sv3 };
        if (c < 15) {
            sv0 = *(const h4*)(sph + (c + 1) * 64 +  0);
            sv1 = *(const h4*)(sph + (c + 1) * 64 + 16);
            sv2 = *(const h4*)(sph + (c + 1) * 64 + 32);
            sv3 = *(const h4*)(sph + (c + 1) * 64 + 48);
        }
        f32x4 a[4];
#pragma unroll
        for (int t = 0; t < 4; t++) {
            a[t] = (f32x4){0.f, 0.f, 0.f, 0.f};
            a[t] = __builtin_amdgcn_mfma_f32_16x16x32_bf16(
                *(const short8*)&sK[cur][t * 16 + l16][quad * 8], aq0, a[t], 0, 0, 0);
            a[t] = __builtin_amdgcn_mfma_f32_16x16x32_bf16(
                *(const short8*)&sK[cur][t * 16 + l16][32 + quad * 8], aq1, a[t], 0, 0, 0);
        }
#pragma unroll
        for (int t = 0; t < 4; t++)
#pragma unroll
            for (int i = 0; i < 4; i++) {
                float s  = a[t][i];
                float sv = (float)svc[t][i];
                float ps = s * sv;
                dn = fmaf(s, s, dn);
                pn = fmaf(ps, ps, pn);
            }
        __syncthreads();
    }
    dn += __shfl_xor(dn, 16, 64); dn += __shfl_xor(dn, 32, 64);
    pn += __shfl_xor(pn, 16, 64); pn += __shfl_xor(pn, 32, 64);
    const float ratio = sqrtf(dn) / fmaxf(sqrtf(pn), 1e-12f);   // per q-row l16

    // ================= sweep 2: bias + online softmax + PV =================
    float m_r = -1e30f, ls = 0.f;
    f32x4 O[4];
#pragma unroll
    for (int dt = 0; dt < 4; dt++) O[dt] = (f32x4){0.f, 0.f, 0.f, 0.f};

    short8 k0 = *(const short8*)(ksrc);
    short8 k1 = *(const short8*)(ksrc + 2048);
    short8 v0 = *(const short8*)(vsrc);
    short8 v1 = *(const short8*)(vsrc + 32768);

    for (int c = 0; c < 16; ++c) {
        __syncthreads();
        *(short8*)&sK[0][sr][sc]      = k0;
        *(short8*)&sK[0][sr + 32][sc] = k1;
        *(short8*)&sV[sr][sc]      = v0;
        *(short8*)&sV[sr + 32][sc] = v1;
        __syncthreads();
        h4 svh[4];
        svh[0] = *(const h4*)(sph + c * 64 +  0);
        svh[1] = *(const h4*)(sph + c * 64 + 16);
        svh[2] = *(const h4*)(sph + c * 64 + 32);
        svh[3] = *(const h4*)(sph + c * 64 + 48);
        if (c < 15) {
            k0 = *(const short8*)(ksrc + (c + 1) * 4096);
            k1 = *(const short8*)(ksrc + (c + 1) * 4096 + 2048);
            v0 = *(const short8*)(vsrc + (c + 1) * 64);
            v1 = *(const short8*)(vsrc + (c + 1) * 64 + 32768);
        }
        f32x4 a[4];
#pragma unroll
        for (int t = 0; t < 4; t++) {
            a[t] = (f32x4){0.f, 0.f, 0.f, 0.f};
            a[t] = __builtin_amdgcn_mfma_f32_16x16x32_bf16(
                *(const short8*)&sK[0][t * 16 + l16][quad * 8], aq0, a[t], 0, 0, 0);
            a[t] = __builtin_amdgcn_mfma_f32_16x16x32_bf16(
                *(const short8*)&sK[0][t * 16 + l16][32 + quad * 8], aq1, a[t], 0, 0, 0);
        }
        // bias + chunk max (per q-row l16)
        float mx = -1e30f;
#pragma unroll
        for (int t = 0; t < 4; t++)
#pragma unroll
            for (int i = 0; i < 4; i++) {
                float s  = a[t][i];
                float sv = (float)svh[t][i];
                float l  = s * fmaf(sv, ratio, 1.0f);
                a[t][i] = l;
                mx = fmaxf(mx, l);
            }
        mx = fmaxf(mx, __shfl_xor(mx, 16, 64));
        mx = fmaxf(mx, __shfl_xor(mx, 32, 64));        // row-uniform chunk max
        const float m_new = fmaxf(m_r, mx);
        const float fo = __expf(m_r - m_new);          // rescale for row l16
        m_r = m_new;
        ls *= fo;
        // O rows are q=quad*4+i (D-layout), fo's row domain is l16 (R5 fix)
        float fov[4];
#pragma unroll
        for (int i = 0; i < 4; i++) fov[i] = __shfl(fo, quad * 4 + i, 16);
#pragma unroll
        for (int dt = 0; dt < 4; dt++) {
            O[dt][0] *= fov[0]; O[dt][1] *= fov[1];
            O[dt][2] *= fov[2]; O[dt][3] *= fov[3];
        }
        // exp + pack P (row l16 domain)
#pragma unroll
        for (int t = 0; t < 4; t++) {
            float p0 = __expf(a[t][0] - m_r);
            float p1 = __expf(a[t][1] - m_r);
            float p2 = __expf(a[t][2] - m_r);
            float p3 = __expf(a[t][3] - m_r);
            ls += (p0 + p1) + (p2 + p3);
            s16x4 pk = { f2bf(p0), f2bf(p1), f2bf(p2), f2bf(p3) };
            *(s16x4*)&sP[wv][l16][t * 16 + quad * 4] = pk;
        }
        // PV (same-wave sP round trip)
#pragma unroll
        for (int kc = 0; kc < 2; kc++) {
            short8 pa = *(const short8*)&sP[wv][l16][kc * 32 + quad * 8];
#pragma unroll
            for (int dt = 0; dt < 4; dt++) {
                short8 vf = *(const short8*)&sV[dt * 16 + l16][kc * 32 + quad * 8];
                O[dt] = __builtin_amdgcn_mfma_f32_16x16x32_bf16(pa, vf, O[dt], 0, 0, 0);
            }
        }
    }
    // final normalization; ls is lane-partial -> row total (row l16)
    ls += __shfl_xor(ls, 16, 64); ls += __shfl_xor(ls, 32, 64);
    const float hsum = hm[0] + hm[1] + hm[2] + hm[3] + hm[4] + hm[5] + hm[6] + hm[7];
    const float rinv = hm[h] * 8.0f / (hsum * ls);     // per l16-row
    if (quad == 0) sred[wv][l16] = rinv;
    __syncthreads();
    float rv[4];
#pragma unroll
    for (int i = 0; i < 4; i++) rv[i] = sred[wv][quad * 4 + i];
#pragma unroll
    for (int dt = 0; dt < 4; dt++)
#pragma unroll
        for (int i = 0; i < 4; i++)
            o[((size_t)(b * 1024 + q0 + wv * 16 + quad * 4 + i)) * 512 + h * 64 + dt * 16 + l16]
                = f2bf(O[dt][i] * rv[i]);
}

// ---------------------------------------------------------------------------
// K3: out = O @ WoT^T + b_out  (M=8192, K=512, N=512), 128x128 tile, fp32 out
// ---------------------------------------------------------------------------
__global__ __launch_bounds__(256) void out_gemm(
    const short* __restrict__ A, const short* __restrict__ BT,
    const float* __restrict__ bias, float* __restrict__ out)
{
    __shared__ short sA[128][32];
    __shared__ short sB[128][32];

    const int tid  = threadIdx.x;
    const int wv   = tid >> 6, lane = tid & 63;
    const int quad = lane >> 4, l16 = lane & 15;
    const int wr = wv >> 1, wc = wv & 1;
    const int m0 = blockIdx.x * 128, n0 = blockIdx.y * 128;

    f32x4 acc[4][4];
#pragma unroll
    for (int i = 0; i < 4; i++)
#pragma unroll
        for (int j = 0; j < 4; j++) acc[i][j] = (f32x4){0.f, 0.f, 0.f, 0.f};

    const short* a_src = A  + (size_t)(m0 + wv * 32 + (lane >> 2)) * 512 + (lane & 3) * 8;
    const short* b_src = BT + (size_t)(n0 + wv * 32 + (lane >> 2)) * 512 + (lane & 3) * 8;
    char* a_dst = (char*)sA + wv * 2048;
    char* b_dst = (char*)sB + wv * 2048;

    for (int ks = 0; ks < 16; ks++) {
        __syncthreads();
        const short* ap = a_src + ks * 32;
        const short* bp = b_src + ks * 32;
        __builtin_amdgcn_global_load_lds((gp1)(ap),            (lp3)(a_dst),        16, 0, 0);
        __builtin_amdgcn_global_load_lds((gp1)(ap + 16 * 512), (lp3)(a_dst + 1024), 16, 0, 0);
        __builtin_amdgcn_global_load_lds((gp1)(bp),            (lp3)(b_dst),        16, 0, 0);
        __builtin_amdgcn_global_load_lds((gp1)(bp + 16 * 512), (lp3)(b_dst + 1024), 16, 0, 0);
        __syncthreads();

        short8 af[4], bf[4];
#pragma unroll
        for (int f = 0; f < 4; f++) {
            af[f] = *(const short8*)&sA[wr * 64 + f * 16 + l16][quad * 8];
            bf[f] = *(const short8*)&sB[wc * 64 + f * 16 + l16][quad * 8];
        }
#pragma unroll
        for (int fm = 0; fm < 4; fm++)
#pragma unroll
            for (int fn = 0; fn < 4; fn++)
                acc[fm][fn] = __builtin_amdgcn_mfma_f32_16x16x32_bf16(
                    af[fm], bf[fn], acc[fm][fn], 0, 0, 0);
    }

#pragma unroll
    for (int fn = 0; fn < 4; fn++) {
        const int gc = n0 + wc * 64 + fn * 16 + l16;
        const float bv = bias[gc];
#pragma unroll
        for (int fm = 0; fm < 4; fm++)
#pragma unroll
            for (int i = 0; i < 4; i++) {
                const int gm = m0 + wr * 64 + fm * 16 + quad * 4 + i;
                out[(size_t)gm * 512 + gc] = acc[fm][fn][i] + bv;
            }
    }
}

// ---------------------------------------------------------------------------
extern "C" void kernel_launch(void* const* d_in, const int* in_sizes, int n_in,
                              void* d_out, int out_size, void* d_ws, size_t ws_size,
                              hipStream_t stream) {
    const float* x    = (const float*)d_in[0];
    const float* spd  = (const float*)d_in[1];
    const float* hm   = (const float*)d_in[2];
    const float* Wqkv = (const float*)d_in[3];
    const float* Wout = (const float*)d_in[4];
    const float* bout = (const float*)d_in[5];
    float* out = (float*)d_out;

    char* ws = (char*)d_ws;
    short* qw  = (short*)(ws);                      // 8 MB  [bh][n][d] bf16 (pre-scaled)
    short* kw  = (short*)(ws + ((size_t)8  << 20)); // 8 MB  [bh][n][d] bf16
    short* vtw = (short*)(ws + ((size_t)16 << 20)); // 8 MB  [bh][d][n] bf16
    short* ow  = (short*)(ws + ((size_t)24 << 20)); // 8 MB  [b][n][h*64+d] bf16
    short* vw  = (short*)(ws + ((size_t)24 << 20)); // 8 MB  [bh][n][d] (overlays ow:
                                                    //   vw dead before attn writes ow)
    short* xb  = (short*)(ws + ((size_t)32 << 20)); // 8 MB  x bf16 [8192][512]
    short* wqT = (short*)(ws + ((size_t)40 << 20)); // 1.5MB Wqkv^T bf16 [1536][512]
    short* woT = (short*)(ws + ((size_t)42 << 20)); // 0.5MB Wout^T bf16 [512][512]
    _Float16* spdh = (_Float16*)(ws + ((size_t)43 << 20)); // 16MB spd fp16

    cvt_bf16<<<4096, 256, 0, stream>>>(x, xb, 8192 * 512 / 4);
    cvt_spd <<<8192, 256, 0, stream>>>(spd, spdh, 8 * 1024 * 1024 / 4);
    tr_w    <<<dim3(8, 24), 256, 0, stream>>>(Wqkv, wqT, 512, 1536);
    tr_w    <<<dim3(8, 8),  256, 0, stream>>>(Wout, woT, 512, 512);

    qkv_gemm<<<dim3(64, 12), 256, 0, stream>>>(xb, wqT, qw, kw, vw);
    tr_v    <<<dim3(16, 64), 256, 0, stream>>>(vw, vtw);
    attn_k  <<<dim3(16, 64), 256, 0, stream>>>(qw, kw, vtw, spdh, hm, ow);
    out_gemm<<<dim3(64, 4),  256, 0, stream>>>(ow, woT, bout, out);
}